// Round 1
// baseline (226.850 us; speedup 1.0000x reference)
//
#include <hip/hip_runtime.h>

typedef __bf16 bf16x8 __attribute__((ext_vector_type(8)));
typedef float f32x4 __attribute__((ext_vector_type(4)));
typedef unsigned short u16;
typedef unsigned int u32;

__device__ __forceinline__ float bf2f(u16 x){ u32 u = ((u32)x)<<16; return __builtin_bit_cast(float,u); }
__device__ __forceinline__ u16 f2bf(float f){ u32 u = __builtin_bit_cast(u32,f); u = (u + 0x7fffu + ((u>>16)&1u)) >> 16; return (u16)u; }

static constexpr float LOG2E = 1.4426950408889634f;

// ---------------- f32 -> bf16 bulk convert (4 elems/thread) ----------------
__global__ void k_cvt(const float* __restrict__ s, u16* __restrict__ d, int n4){
  int i = blockIdx.x*256 + threadIdx.x;
  if (i >= n4) return;
  float4 v = reinterpret_cast<const float4*>(s)[i];
  ushort4 o = make_ushort4(f2bf(v.x), f2bf(v.y), f2bf(v.z), f2bf(v.w));
  reinterpret_cast<ushort4*>(d)[i] = o;
}

// ------- depthwise 15-tap conv along token axis on pre-scaled Q ------------
// Q' = q~ + conv_n(q~); pe_b dropped (softmax shift invariance).
__global__ void k_qconv(const u16* __restrict__ q, u16* __restrict__ qp, const float* __restrict__ pw){
  int idx = blockIdx.x*256 + threadIdx.x;         // [0, 64*1024*64)
  int d = idx & 63, n = (idx>>6)&1023, bh = idx>>16, h = bh&7;
  const u16* base = q + (long)bh*65536;
  float acc = bf2f(base[n*64+d]);
  #pragma unroll
  for (int t=0;t<15;t++){
    int nn = n - 7 + t;
    if (nn >= 0 && nn < 1024) acc += pw[h*15+t]*bf2f(base[nn*64+d]);
  }
  qp[idx] = f2bf(acc);  // idx == bh*65536 + n*64 + d
}

// ---------------- 128x128 tile bf16 MFMA GEMM, C = A * Bw^T + bias ---------
// A: [M x 512] bf16 row-major; Bw: [Ncols x 512] bf16 row-major (i.e. B^T).
// MODE 0: qkv epilogue -> scatter q~(scaled), K, V^T. MODE 1: f32 out.
template<int MODE>
__global__ __launch_bounds__(256) void k_gemm(
  const u16* __restrict__ A, const u16* __restrict__ Bw, const float* __restrict__ bias,
  u16* __restrict__ qo, u16* __restrict__ ko, u16* __restrict__ vo, float* __restrict__ co)
{
  constexpr int K = 512;
  __shared__ __align__(16) u16 lA[128*32];
  __shared__ __align__(16) u16 lB[128*32];
  const int T = threadIdx.x;
  const int w = T>>6, lane = T&63, g = lane>>4, cl = lane&15;
  const int i0 = blockIdx.y*128, j0 = blockIdx.x*128;
  const int wr = (w>>1)*64, wc = (w&1)*64;
  const int sr = T>>2, sk = 8*(T&3);
  f32x4 acc[4][4];
  #pragma unroll
  for (int a=0;a<4;a++)
    #pragma unroll
    for (int b=0;b<4;b++) acc[a][b] = (f32x4){0.f,0.f,0.f,0.f};

  for (int k0=0;k0<K;k0+=32){
    uint4 ra0 = *reinterpret_cast<const uint4*>(A + (long)(i0+sr)*K + k0 + sk);
    uint4 ra1 = *reinterpret_cast<const uint4*>(A + (long)(i0+64+sr)*K + k0 + sk);
    uint4 rb0 = *reinterpret_cast<const uint4*>(Bw + (long)(j0+sr)*K + k0 + sk);
    uint4 rb1 = *reinterpret_cast<const uint4*>(Bw + (long)(j0+64+sr)*K + k0 + sk);
    __syncthreads();
    *reinterpret_cast<uint4*>(lA + sr*32 + sk)      = ra0;
    *reinterpret_cast<uint4*>(lA + (64+sr)*32 + sk) = ra1;
    *reinterpret_cast<uint4*>(lB + sr*32 + sk)      = rb0;
    *reinterpret_cast<uint4*>(lB + (64+sr)*32 + sk) = rb1;
    __syncthreads();
    bf16x8 af[4], bfr[4];
    #pragma unroll
    for (int mf=0;mf<4;mf++) af[mf]  = *reinterpret_cast<const bf16x8*>(lA + (wr+16*mf+cl)*32 + 8*g);
    #pragma unroll
    for (int nf=0;nf<4;nf++) bfr[nf] = *reinterpret_cast<const bf16x8*>(lB + (wc+16*nf+cl)*32 + 8*g);
    #pragma unroll
    for (int mf=0;mf<4;mf++)
      #pragma unroll
      for (int nf=0;nf<4;nf++)
        acc[mf][nf] = __builtin_amdgcn_mfma_f32_16x16x32_bf16(af[mf], bfr[nf], acc[mf][nf], 0,0,0);
  }

  #pragma unroll
  for (int mf=0;mf<4;mf++){
    #pragma unroll
    for (int nf=0;nf<4;nf++){
      const int col = j0 + wc + 16*nf + cl;
      const float bb = bias[col];
      const int row0 = i0 + wr + 16*mf + 4*g;
      if (MODE==0){
        const int part = col>>9, h=(col>>6)&7, dd=col&63;
        const int b = row0>>10, n0 = row0&1023, bh = b*8+h;
        if (part==2){
          // V^T: 4 consecutive n -> one 8B store
          ushort4 pk = make_ushort4(f2bf(acc[mf][nf][0]+bb), f2bf(acc[mf][nf][1]+bb),
                                    f2bf(acc[mf][nf][2]+bb), f2bf(acc[mf][nf][3]+bb));
          *reinterpret_cast<ushort4*>(vo + ((long)bh*64+dd)*1024 + n0) = pk;
        } else {
          #pragma unroll
          for (int e=0;e<4;e++){
            float v = acc[mf][nf][e] + bb;
            if (part==0) qo[((long)bh*1024+n0+e)*64+dd] = f2bf(v*0.125f);  // SCALE = 64^-0.5
            else         ko[((long)bh*1024+n0+e)*64+dd] = f2bf(v);
          }
        }
      } else {
        #pragma unroll
        for (int e=0;e<4;e++)
          co[(long)(row0+e)*512 + col] = acc[mf][nf][e] + bb;
      }
    }
  }
}

// ---------------- fused window attention (flash-style) ---------------------
// 512 blocks: (b,h,rowblock of 128). 8 waves x 16 rows. m-tiles of 64.
__global__ __launch_bounds__(512) void k_attn(
  const u16* __restrict__ Qp, const u16* __restrict__ Kb, const u16* __restrict__ VT,
  const float* __restrict__ rel_table, u16* __restrict__ Ao)
{
  __shared__ float rel[3969];
  __shared__ __align__(16) u16 ps[8*1024];   // per-wave 16x64 bf16 P stage (XOR-swizzled)
  const int bid = blockIdx.x;
  const int b = bid>>6, h=(bid>>3)&7, rb = bid&7, bh = b*8+h;
  const int T = threadIdx.x, w=T>>6, lane=T&63, g=lane>>4, cl=lane&15;
  for (int i=T;i<3969;i+=512) rel[i] = rel_table[i*8+h];
  const int rowbase = rb*128 + w*16;
  const u16* Qrow = Qp + ((long)bh*1024 + rowbase + cl)*64;
  const bf16x8 qf0 = *reinterpret_cast<const bf16x8*>(Qrow + 8*g);
  const bf16x8 qf1 = *reinterpret_cast<const bf16x8*>(Qrow + 32 + 8*g);
  int rt[4];
  #pragma unroll
  for (int e=0;e<4;e++){ int gr = rowbase + 4*g + e; rt[e] = (gr>>5)*63 + (gr&31) + 1984; }
  float mrun[4], lrun[4];
  #pragma unroll
  for (int e=0;e<4;e++){ mrun[e] = -1e30f; lrun[e] = 0.f; }
  f32x4 oacc[4];
  #pragma unroll
  for (int c=0;c<4;c++) oacc[c] = (f32x4){0.f,0.f,0.f,0.f};
  u16* psw = ps + w*1024;
  const u16* Kbh = Kb + (long)bh*65536;
  const u16* Vbh = VT + (long)bh*65536;
  __syncthreads();

  for (int m0=0;m0<1024;m0+=64){
    f32x4 sacc[4];
    #pragma unroll
    for (int c=0;c<4;c++) sacc[c] = (f32x4){0.f,0.f,0.f,0.f};
    #pragma unroll
    for (int c=0;c<4;c++){
      const u16* Krow = Kbh + (m0 + 16*c + cl)*64;
      bf16x8 kf0 = *reinterpret_cast<const bf16x8*>(Krow + 8*g);
      bf16x8 kf1 = *reinterpret_cast<const bf16x8*>(Krow + 32 + 8*g);
      sacc[c] = __builtin_amdgcn_mfma_f32_16x16x32_bf16(qf0, kf0, sacc[c],0,0,0);
      sacc[c] = __builtin_amdgcn_mfma_f32_16x16x32_bf16(qf1, kf1, sacc[c],0,0,0);
    }
    float s[4][4];                       // [c][e]
    #pragma unroll
    for (int c=0;c<4;c++){
      int col = m0 + 16*c + cl;
      int ct = (col>>5)*63 + (col&31);
      #pragma unroll
      for (int e=0;e<4;e++) s[c][e] = sacc[c][e] + rel[rt[e]-ct];
    }
    float tmx[4];
    #pragma unroll
    for (int e=0;e<4;e++) tmx[e] = fmaxf(fmaxf(s[0][e],s[1][e]), fmaxf(s[2][e],s[3][e]));
    #pragma unroll
    for (int mk=1;mk<16;mk<<=1)
      #pragma unroll
      for (int e=0;e<4;e++) tmx[e] = fmaxf(tmx[e], __shfl_xor(tmx[e], mk, 64));
    float nm[4], al[4], rs[4];
    #pragma unroll
    for (int e=0;e<4;e++){
      nm[e] = fmaxf(mrun[e], tmx[e]);
      al[e] = exp2f((mrun[e]-nm[e])*LOG2E);
      mrun[e] = nm[e];
    }
    #pragma unroll
    for (int c=0;c<4;c++)
      #pragma unroll
      for (int e=0;e<4;e++) s[c][e] = exp2f((s[c][e]-nm[e])*LOG2E);
    #pragma unroll
    for (int e=0;e<4;e++) rs[e] = (s[0][e]+s[1][e])+(s[2][e]+s[3][e]);
    #pragma unroll
    for (int mk=1;mk<16;mk<<=1)
      #pragma unroll
      for (int e=0;e<4;e++) rs[e] += __shfl_xor(rs[e], mk, 64);
    #pragma unroll
    for (int e=0;e<4;e++) lrun[e] = lrun[e]*al[e] + rs[e];
    #pragma unroll
    for (int c=0;c<4;c++)
      #pragma unroll
      for (int e=0;e<4;e++) oacc[c][e] *= al[e];
    // stage P (bf16) to swizzled LDS for the PV A-operand
    #pragma unroll
    for (int c=0;c<4;c++)
      #pragma unroll
      for (int e=0;e<4;e++){
        int row = 4*g+e, col = 16*c+cl;
        int byt = (row*128 + col*2) ^ ((row&7)<<4);
        *reinterpret_cast<u16*>(reinterpret_cast<char*>(psw)+byt) = f2bf(s[c][e]);
      }
    #pragma unroll
    for (int ks=0;ks<2;ks++){
      int byt = (cl*128 + (32*ks+8*g)*2) ^ ((cl&7)<<4);
      bf16x8 af = *reinterpret_cast<const bf16x8*>(reinterpret_cast<char*>(psw)+byt);
      #pragma unroll
      for (int c2=0;c2<4;c2++){
        bf16x8 vf = *reinterpret_cast<const bf16x8*>(Vbh + (16*c2+cl)*1024 + m0 + 32*ks + 8*g);
        oacc[c2] = __builtin_amdgcn_mfma_f32_16x16x32_bf16(af, vf, oacc[c2],0,0,0);
      }
    }
  }
  #pragma unroll
  for (int e=0;e<4;e++){
    float inv = 1.0f/lrun[e];
    int grow = rowbase + 4*g + e;
    #pragma unroll
    for (int c2=0;c2<4;c2++)
      Ao[((long)b*1024+grow)*512 + h*64 + 16*c2 + cl] = f2bf(oacc[c2][e]*inv);
  }
}

extern "C" void kernel_launch(void* const* d_in, const int* in_sizes, int n_in,
                              void* d_out, int out_size, void* d_ws, size_t ws_size,
                              hipStream_t stream)
{
  const float* x         = (const float*)d_in[0];
  const float* w_qkv     = (const float*)d_in[1];
  const float* b_qkv     = (const float*)d_in[2];
  const float* w_proj    = (const float*)d_in[3];
  const float* b_proj    = (const float*)d_in[4];
  const float* rel_table = (const float*)d_in[5];
  const float* pe_w      = (const float*)d_in[6];
  // d_in[7] (pe_b) intentionally unused: constant along softmax axis.
  (void)in_sizes; (void)n_in; (void)out_size; (void)ws_size;

  u16* ws    = (u16*)d_ws;
  u16* x_bf  = ws;                  // 8192*512
  u16* wq_bf = x_bf  + 4194304;     // 1536*512
  u16* wp_bf = wq_bf + 786432;      // 512*512
  u16* q_bf  = wp_bf + 262144;      // [B,H,N,64] pre-scaled
  u16* k_bf  = q_bf  + 4194304;     // [B,H,N,64]
  u16* vt_bf = k_bf  + 4194304;     // [B,H,64,N]
  u16* qp_bf = vt_bf + 4194304;     // Q' = q~ + conv(q~)
  u16* ao_bf = qp_bf + 4194304;     // attention out [B,N,C]

  k_cvt<<<4096,256,0,stream>>>(x, x_bf, 1048576);
  k_cvt<<<768,256,0,stream>>>(w_qkv, wq_bf, 196608);
  k_cvt<<<256,256,0,stream>>>(w_proj, wp_bf, 65536);
  k_gemm<0><<<dim3(12,64),256,0,stream>>>(x_bf, wq_bf, b_qkv, q_bf, k_bf, vt_bf, nullptr);
  k_qconv<<<16384,256,0,stream>>>(q_bf, qp_bf, pe_w);
  k_attn<<<512,512,0,stream>>>(qp_bf, k_bf, vt_bf, rel_table, ao_bf);
  k_gemm<1><<<dim3(4,64),256,0,stream>>>(ao_bf, wp_bf, b_proj, nullptr, nullptr, nullptr, (float*)d_out);
}